// Round 2
// baseline (672.993 us; speedup 1.0000x reference)
//
#include <hip/hip_runtime.h>
#include <math.h>

// Problem constants (B=4, L=4096, n=4, C=1024) — all tensors fp32
#define DTOT   4096          // n*C
#define NTOK   16384         // B*L
#define NJ     24            // 4 pre + 4 post + 16 res dot products
#define NG     25            // NJ dots + sumsq
#define DC     128           // d-elements per chunk in dots kernel
#define NCHUNK (DTOT / DC)   // 32
#define TOKB   512           // tokens per dots-block (256 threads x 2 tokens)

// ---------------------------------------------------------------------------
// Kernel 0: Wt[d][j] = W[j][d] * norm_w[d], j: 0-3 pre, 4-7 post, 8-23 res
// ---------------------------------------------------------------------------
__global__ void prep_kernel(const float* __restrict__ Wpre,
                            const float* __restrict__ Wpost,
                            const float* __restrict__ Wres,
                            const float* __restrict__ nw,
                            float* __restrict__ Wt) {
    int i = blockIdx.x * 256 + threadIdx.x;   // over 4096*24
    if (i >= DTOT * NJ) return;
    int d = i / NJ;
    int j = i - d * NJ;
    float w;
    if (j < 4)       w = Wpre [(size_t)j       * DTOT + d];
    else if (j < 8)  w = Wpost[(size_t)(j - 4) * DTOT + d];
    else             w = Wres [(size_t)(j - 8) * DTOT + d];
    Wt[i] = w * nw[d];
}

// ---------------------------------------------------------------------------
// Kernel 1: partial dots + sumsq per (token, d-chunk).
// grid = (NTOK/TOKB, NCHUNK) = 32 x 32 -> 1024 blocks = 4 blocks/CU,
// 16 waves/CU. 2 tokens/thread so each wave-uniform LDS weight broadcast
// (24 x ds_read_b128 per 4 d) feeds TWO accumulator sets (LDS pipe demand
// ~25us < 41us x-read BW floor). x loads software-pipelined one group
// (8 d-elements) ahead: 4 float4 in flight/wave -> latency hidden at
// 16 waves/CU.
// Gpart layout: [chunk][j(0..24)][token]  (coalesced stores across lanes)
// ---------------------------------------------------------------------------
__global__ __launch_bounds__(256, 4) void dots_kernel(
        const float* __restrict__ x,
        const float* __restrict__ Wt,
        float* __restrict__ Gpart) {
    __shared__ float wlds[DC * NJ];   // 128*24*4 = 12288 B

    const int tid = threadIdx.x;
    const int tg  = blockIdx.x;       // token group (0..31)
    const int ch  = blockIdx.y;       // d chunk (0..31)

    // Stage this chunk's weights into LDS (flat float4 copy; base 16B aligned)
    {
        const float4* src = (const float4*)(Wt + (size_t)ch * DC * NJ);
        float4* dst = (float4*)wlds;
        #pragma unroll
        for (int i = 0; i < (DC * NJ / 4) / 256; ++i)   // 3 iterations
            dst[tid + 256 * i] = src[tid + 256 * i];
    }
    __syncthreads();

    const int tok0 = tg * TOKB + tid;
    const int tok1 = tok0 + 256;
    const float4* __restrict__ x0 =
        (const float4*)(x + (size_t)tok0 * DTOT + (size_t)ch * DC);
    const float4* __restrict__ x1 =
        (const float4*)(x + (size_t)tok1 * DTOT + (size_t)ch * DC);

    float pa[NG], pb[NG];
    #pragma unroll
    for (int j = 0; j < NG; ++j) { pa[j] = 0.f; pb[j] = 0.f; }

    // group = 8 d-elements (2 float4 per token); 16 groups; prefetch next
    float4 a0 = x0[0], a1 = x0[1];
    float4 b0 = x1[0], b1 = x1[1];

    for (int g = 0; g < DC / 8; ++g) {
        float4 na0 = a0, na1 = a1, nb0 = b0, nb1 = b1;
        if (g < DC / 8 - 1) {
            na0 = x0[2 * g + 2];
            na1 = x0[2 * g + 3];
            nb0 = x1[2 * g + 2];
            nb1 = x1[2 * g + 3];
        }

        const float xs[8] = { a0.x, a0.y, a0.z, a0.w, a1.x, a1.y, a1.z, a1.w };
        const float ys[8] = { b0.x, b0.y, b0.z, b0.w, b1.x, b1.y, b1.z, b1.w };

        #pragma unroll
        for (int k = 0; k < 8; ++k) {
            const float xa = xs[k];
            const float xb = ys[k];
            // 96 B row, 16B aligned: 6 x ds_read_b128, wave-uniform broadcast
            const float4* __restrict__ wv =
                (const float4*)(wlds + (g * 8 + k) * NJ);
            #pragma unroll
            for (int jv = 0; jv < 6; ++jv) {
                const float4 w = wv[jv];
                pa[4*jv+0] += xa * w.x;  pb[4*jv+0] += xb * w.x;
                pa[4*jv+1] += xa * w.y;  pb[4*jv+1] += xb * w.y;
                pa[4*jv+2] += xa * w.z;  pb[4*jv+2] += xb * w.z;
                pa[4*jv+3] += xa * w.w;  pb[4*jv+3] += xb * w.w;
            }
            pa[NG-1] += xa * xa;
            pb[NG-1] += xb * xb;
        }

        a0 = na0; a1 = na1; b0 = nb0; b1 = nb1;
    }

    float* gp = Gpart + (size_t)ch * NG * NTOK;
    #pragma unroll
    for (int j = 0; j < NG; ++j) {
        gp[(size_t)j * NTOK + tok0] = pa[j];
        gp[(size_t)j * NTOK + tok1] = pb[j];
    }
}

// ---------------------------------------------------------------------------
// Kernel 2: wave-per-token, barrier-free. 1024-thread blocks = 16 tokens per
// block so the Gpart gather (lane j reads [c][j][token], token-major stride)
// hits full 64B lines via L1 across the block's 16 consecutive tokens
// (was 4 tokens/block -> 4x fetch inflation).
// Lanes 0..24 reduce chunks; __shfl all-gather; all 64 lanes compute
// gates + Cayley redundantly (no barriers, no LDS); each lane writes 64
// output channels.
// ---------------------------------------------------------------------------
__global__ __launch_bounds__(1024) void out_kernel(
        const float* __restrict__ x,
        const float* __restrict__ Gpart,
        const float* __restrict__ bpre,
        const float* __restrict__ bpost,
        const float* __restrict__ bres,
        const float* __restrict__ apre,
        const float* __restrict__ apost,
        const float* __restrict__ ares,
        float* __restrict__ out) {
    const int lane  = threadIdx.x & 63;
    const int token = blockIdx.x * 16 + (threadIdx.x >> 6);

    // Phase 1: per-gate chunk reduction (lanes 0..24 active, 32 indep loads)
    float s = 0.f;
    if (lane < NG) {
        const float* gp = Gpart + (size_t)lane * NTOK + token;
        #pragma unroll
        for (int c = 0; c < NCHUNK; ++c)
            s += gp[(size_t)c * NG * NTOK];
    }

    // All-gather the 25 sums to every lane (wave-wide, no LDS, no barrier)
    float g[NG];
    #pragma unroll
    for (int j = 0; j < NG; ++j) g[j] = __shfl(s, j, 64);

    // Phase 2: gates + Cayley — computed redundantly by all 64 lanes
    const float inv = rsqrtf(g[NG-1] * (1.0f / DTOT) + 1e-6f);
    const float a_pre  = apre[0];
    const float a_post = apost[0];
    const float a_res  = ares[0];

    float hpre[4], hpost[4];
    #pragma unroll
    for (int i = 0; i < 4; ++i) {
        float z1 = a_pre  * g[i]     * inv + bpre[i];
        hpre[i]  = 1.f / (1.f + __expf(-z1));
        float z2 = a_post * g[4 + i] * inv + bpost[i];
        hpost[i] = 2.f / (1.f + __expf(-z2));
    }

    float M[4][4];
    #pragma unroll
    for (int i = 0; i < 4; ++i)
        #pragma unroll
        for (int j = 0; j < 4; ++j)
            M[i][j] = a_res * g[8 + i * 4 + j] * inv + bres[i * 4 + j];

    // Cayley: Q = (I - S)^{-1} (I + S), S = 0.5 (M - M^T)
    float A[4][8];
    #pragma unroll
    for (int i = 0; i < 4; ++i)
        #pragma unroll
        for (int j = 0; j < 4; ++j) {
            float S = 0.5f * (M[i][j] - M[j][i]);
            float I = (i == j) ? 1.f : 0.f;
            A[i][j]     = I - S;
            A[i][4 + j] = I + S;
        }
    // Gauss-Jordan; (I - S) with small skew S is diag-dominant, no pivoting
    #pragma unroll
    for (int k = 0; k < 4; ++k) {
        float pv = 1.f / A[k][k];
        #pragma unroll
        for (int c = 0; c < 8; ++c) A[k][c] *= pv;
        #pragma unroll
        for (int i = 0; i < 4; ++i) {
            if (i == k) continue;
            float f = A[i][k];
            #pragma unroll
            for (int c = 0; c < 8; ++c) A[i][c] -= f * A[k][c];
        }
    }
    // fused coefficients: out[m] = sum_n (Q[m][n] + hpost[m]*hpre[n]) x[n]
    float cf[16];
    #pragma unroll
    for (int m = 0; m < 4; ++m)
        #pragma unroll
        for (int n = 0; n < 4; ++n)
            cf[m * 4 + n] = A[m][4 + n] + hpost[m] * hpre[n];

    // Phase 3: outputs — lane covers 4 float4 positions per n-row (coalesced)
    const float* xt = x + (size_t)token * DTOT;
    float* ot = out + (size_t)token * DTOT;

    #pragma unroll
    for (int cc = 0; cc < 4; ++cc) {
        const int c0 = cc * 256 + lane * 4;
        float4 xv[4];
        #pragma unroll
        for (int n = 0; n < 4; ++n)
            xv[n] = *(const float4*)(xt + n * 1024 + c0);
        #pragma unroll
        for (int m = 0; m < 4; ++m) {
            float4 o;
            o.x = cf[m*4+0] * xv[0].x; o.y = cf[m*4+0] * xv[0].y;
            o.z = cf[m*4+0] * xv[0].z; o.w = cf[m*4+0] * xv[0].w;
            #pragma unroll
            for (int n = 1; n < 4; ++n) {
                const float c = cf[m * 4 + n];
                o.x += c * xv[n].x;
                o.y += c * xv[n].y;
                o.z += c * xv[n].z;
                o.w += c * xv[n].w;
            }
            *(float4*)(ot + m * 1024 + c0) = o;
        }
    }
}

// ---------------------------------------------------------------------------
extern "C" void kernel_launch(void* const* d_in, const int* in_sizes, int n_in,
                              void* d_out, int out_size, void* d_ws, size_t ws_size,
                              hipStream_t stream) {
    const float* x     = (const float*)d_in[0];
    const float* nw    = (const float*)d_in[1];
    const float* Wpre  = (const float*)d_in[2];
    const float* Wpost = (const float*)d_in[3];
    const float* Wres  = (const float*)d_in[4];
    const float* bpre  = (const float*)d_in[5];
    const float* bpost = (const float*)d_in[6];
    const float* bres  = (const float*)d_in[7];
    const float* apre  = (const float*)d_in[8];
    const float* apost = (const float*)d_in[9];
    const float* ares  = (const float*)d_in[10];
    float* out = (float*)d_out;

    // workspace: Wt (4096*24 fp32 = 384KB) | Gpart (32*25*16384 fp32 ~ 52.4MB)
    float* Wt    = (float*)d_ws;
    float* Gpart = (float*)((char*)d_ws + (size_t)DTOT * NJ * sizeof(float));

    prep_kernel<<<(DTOT * NJ + 255) / 256, 256, 0, stream>>>(Wpre, Wpost, Wres, nw, Wt);

    dim3 ga(NTOK / TOKB, NCHUNK);   // 32 x 32
    dots_kernel<<<ga, 256, 0, stream>>>(x, Wt, Gpart);

    out_kernel<<<NTOK / 16, 1024, 0, stream>>>(x, Gpart, bpre, bpost, bres,
                                               apre, apost, ares, out);
}

// Round 3
// 566.069 us; speedup vs baseline: 1.1889x; 1.1889x over previous
//
#include <hip/hip_runtime.h>
#include <math.h>

// Problem constants (B=4, L=4096, n=4, C=1024) — all tensors fp32
#define DTOT   4096          // n*C
#define NTOK   16384         // B*L
#define NJ     24            // 4 pre + 4 post + 16 res dot products
#define NG     25            // NJ dots + sumsq
#define DC     256           // d-elements per chunk in dots kernel
#define NCHUNK (DTOT / DC)   // 16
#define TPB    32            // tokens per dots-block (4 waves x 8 tokens)

// ---------------------------------------------------------------------------
// Kernel 0: Wtj[j][d] = W[j][d] * norm_w[d]  (j-major, same layout as inputs)
// i = j*DTOT + d, fully coalesced read and write.
// ---------------------------------------------------------------------------
__global__ void prep_kernel(const float* __restrict__ Wpre,
                            const float* __restrict__ Wpost,
                            const float* __restrict__ Wres,
                            const float* __restrict__ nw,
                            float* __restrict__ Wtj) {
    int i = blockIdx.x * 256 + threadIdx.x;   // over 24*4096
    if (i >= NJ * DTOT) return;
    int j = i / DTOT;
    int d = i - j * DTOT;
    float w;
    if (j < 4)       w = Wpre [i];
    else if (j < 8)  w = Wpost[i - 4 * DTOT];
    else             w = Wres [i - 8 * DTOT];
    Wtj[i] = w * nw[d];
}

// ---------------------------------------------------------------------------
// Kernel 1: partial dots + sumsq per (token, d-chunk).
// Lane decomposition: lane = t8*8 + dp  (t8 = token-sub, dp = d-slot).
// A wave's x-load instruction covers 8 token rows x one aligned 128B line
// (dp*16B within the 128B) -> zero over-fetch, dense DRAM bursts.
// Round-2 failure mode (lane=token, 64 lines/instr 16KB apart, 16-32B used
// per visit -> 2.0x FETCH inflation, 3.2TB/s) is eliminated by construction.
// Weights staged j-major [24][256] in LDS; per-(j,i) read is 8 distinct 16B
// rows covering all 32 banks once -> conflict-free ds_read_b128.
// Cross-dp reduce: 3x shfl_xor. grid = (512, 16) = 8192 blocks.
// ---------------------------------------------------------------------------
__global__ __launch_bounds__(256, 5) void dots_kernel(
        const float* __restrict__ x,
        const float* __restrict__ Wtj,
        float* __restrict__ Gpart) {
    __shared__ float wlds[NJ * DC];   // 24*256*4 = 24576 B

    const int tid = threadIdx.x;
    const int ch  = blockIdx.y;       // d chunk (0..15)

    // Stage weights: 24 rows x 256 floats = 1536 float4
    {
        const float4* src = (const float4*)Wtj;   // [j][DTOT/4]
        float4* dst = (float4*)wlds;
        #pragma unroll
        for (int r = 0; r < 6; ++r) {
            int idx = r * 256 + tid;              // 0..1535
            int j = idx >> 6;                     // /64
            int f = idx & 63;
            dst[idx] = src[(size_t)j * (DTOT / 4) + ch * (DC / 4) + f];
        }
    }
    __syncthreads();

    const int w    = tid >> 6;        // wave 0..3
    const int lane = tid & 63;
    const int t8   = lane >> 3;       // 0..7 token-sub
    const int dp   = lane & 7;        // 0..7 d-slot
    const int tok  = blockIdx.x * TPB + w * 8 + t8;

    const float4* __restrict__ xp =
        (const float4*)(x + (size_t)tok * DTOT + ch * DC);
    const float4* __restrict__ wl4 = (const float4*)wlds;   // [j][64]

    float acc[NG];
    #pragma unroll
    for (int j = 0; j < NG; ++j) acc[j] = 0.f;

    float4 xv = xp[dp];
    #pragma unroll
    for (int i = 0; i < 8; ++i) {
        float4 nx = xv;
        if (i < 7) nx = xp[(i + 1) * 8 + dp];     // prefetch next 128B line
        const int base = i * 8 + dp;
        #pragma unroll
        for (int j = 0; j < NJ; ++j) {
            const float4 w4 = wl4[j * 64 + base];
            acc[j] += xv.x * w4.x + xv.y * w4.y + xv.z * w4.z + xv.w * w4.w;
        }
        acc[NG - 1] += xv.x * xv.x + xv.y * xv.y + xv.z * xv.z + xv.w * xv.w;
        xv = nx;
    }

    // reduce the 8 dp-slots (lane bits 0..2) -> token totals
    #pragma unroll
    for (int j = 0; j < NG; ++j) {
        float v = acc[j];
        v += __shfl_xor(v, 1, 64);
        v += __shfl_xor(v, 2, 64);
        v += __shfl_xor(v, 4, 64);
        acc[j] = v;
    }

    if (dp == 0) {
        float* gp = Gpart + (size_t)ch * NG * NTOK + tok;
        #pragma unroll
        for (int j = 0; j < NG; ++j)
            gp[(size_t)j * NTOK] = acc[j];
    }
}

// ---------------------------------------------------------------------------
// Kernel 2: wave-per-token, barrier-free. 1024-thread blocks = 16 consecutive
// tokens per block (full-line Gpart gather via L1). Token order REVERSED so
// the first x re-reads hit what dots_kernel left resident in the 256MB L3
// (x = 268MB streams through L3; tail tokens are still warm).
// Lanes 0..24 reduce chunks; __shfl all-gather; all 64 lanes compute
// gates + Cayley redundantly; each lane writes 64 output channels.
// ---------------------------------------------------------------------------
__global__ __launch_bounds__(1024) void out_kernel(
        const float* __restrict__ x,
        const float* __restrict__ Gpart,
        const float* __restrict__ bpre,
        const float* __restrict__ bpost,
        const float* __restrict__ bres,
        const float* __restrict__ apre,
        const float* __restrict__ apost,
        const float* __restrict__ ares,
        float* __restrict__ out) {
    const int lane  = threadIdx.x & 63;
    const int token = (NTOK - 16 - blockIdx.x * 16) + (threadIdx.x >> 6);

    // Phase 1: per-gate chunk reduction (lanes 0..24 active, 16 indep loads)
    float s = 0.f;
    if (lane < NG) {
        const float* gp = Gpart + (size_t)lane * NTOK + token;
        #pragma unroll
        for (int c = 0; c < NCHUNK; ++c)
            s += gp[(size_t)c * NG * NTOK];
    }

    // All-gather the 25 sums to every lane (wave-wide, no LDS, no barrier)
    float g[NG];
    #pragma unroll
    for (int j = 0; j < NG; ++j) g[j] = __shfl(s, j, 64);

    // Phase 2: gates + Cayley — computed redundantly by all 64 lanes
    const float inv = rsqrtf(g[NG-1] * (1.0f / DTOT) + 1e-6f);
    const float a_pre  = apre[0];
    const float a_post = apost[0];
    const float a_res  = ares[0];

    float hpre[4], hpost[4];
    #pragma unroll
    for (int i = 0; i < 4; ++i) {
        float z1 = a_pre  * g[i]     * inv + bpre[i];
        hpre[i]  = 1.f / (1.f + __expf(-z1));
        float z2 = a_post * g[4 + i] * inv + bpost[i];
        hpost[i] = 2.f / (1.f + __expf(-z2));
    }

    float M[4][4];
    #pragma unroll
    for (int i = 0; i < 4; ++i)
        #pragma unroll
        for (int j = 0; j < 4; ++j)
            M[i][j] = a_res * g[8 + i * 4 + j] * inv + bres[i * 4 + j];

    // Cayley: Q = (I - S)^{-1} (I + S), S = 0.5 (M - M^T)
    float A[4][8];
    #pragma unroll
    for (int i = 0; i < 4; ++i)
        #pragma unroll
        for (int j = 0; j < 4; ++j) {
            float S = 0.5f * (M[i][j] - M[j][i]);
            float I = (i == j) ? 1.f : 0.f;
            A[i][j]     = I - S;
            A[i][4 + j] = I + S;
        }
    // Gauss-Jordan; (I - S) with small skew S is diag-dominant, no pivoting
    #pragma unroll
    for (int k = 0; k < 4; ++k) {
        float pv = 1.f / A[k][k];
        #pragma unroll
        for (int c = 0; c < 8; ++c) A[k][c] *= pv;
        #pragma unroll
        for (int i = 0; i < 4; ++i) {
            if (i == k) continue;
            float f = A[i][k];
            #pragma unroll
            for (int c = 0; c < 8; ++c) A[i][c] -= f * A[k][c];
        }
    }
    // fused coefficients: out[m] = sum_n (Q[m][n] + hpost[m]*hpre[n]) x[n]
    float cf[16];
    #pragma unroll
    for (int m = 0; m < 4; ++m)
        #pragma unroll
        for (int n = 0; n < 4; ++n)
            cf[m * 4 + n] = A[m][4 + n] + hpost[m] * hpre[n];

    // Phase 3: outputs — lane covers 4 float4 positions per n-row (coalesced)
    const float* xt = x + (size_t)token * DTOT;
    float* ot = out + (size_t)token * DTOT;

    #pragma unroll
    for (int cc = 0; cc < 4; ++cc) {
        const int c0 = cc * 256 + lane * 4;
        float4 xv[4];
        #pragma unroll
        for (int n = 0; n < 4; ++n)
            xv[n] = *(const float4*)(xt + n * 1024 + c0);
        #pragma unroll
        for (int m = 0; m < 4; ++m) {
            float4 o;
            o.x = cf[m*4+0] * xv[0].x; o.y = cf[m*4+0] * xv[0].y;
            o.z = cf[m*4+0] * xv[0].z; o.w = cf[m*4+0] * xv[0].w;
            #pragma unroll
            for (int n = 1; n < 4; ++n) {
                const float c = cf[m * 4 + n];
                o.x += c * xv[n].x;
                o.y += c * xv[n].y;
                o.z += c * xv[n].z;
                o.w += c * xv[n].w;
            }
            *(float4*)(ot + m * 1024 + c0) = o;
        }
    }
}

// ---------------------------------------------------------------------------
extern "C" void kernel_launch(void* const* d_in, const int* in_sizes, int n_in,
                              void* d_out, int out_size, void* d_ws, size_t ws_size,
                              hipStream_t stream) {
    const float* x     = (const float*)d_in[0];
    const float* nw    = (const float*)d_in[1];
    const float* Wpre  = (const float*)d_in[2];
    const float* Wpost = (const float*)d_in[3];
    const float* Wres  = (const float*)d_in[4];
    const float* bpre  = (const float*)d_in[5];
    const float* bpost = (const float*)d_in[6];
    const float* bres  = (const float*)d_in[7];
    const float* apre  = (const float*)d_in[8];
    const float* apost = (const float*)d_in[9];
    const float* ares  = (const float*)d_in[10];
    float* out = (float*)d_out;

    // workspace: Wtj (24*4096 fp32 = 384KB) | Gpart (16*25*16384 fp32 ~ 26.2MB)
    float* Wtj   = (float*)d_ws;
    float* Gpart = (float*)((char*)d_ws + (size_t)NJ * DTOT * sizeof(float));

    prep_kernel<<<(NJ * DTOT + 255) / 256, 256, 0, stream>>>(Wpre, Wpost, Wres, nw, Wtj);

    dim3 ga(NTOK / TPB, NCHUNK);   // 512 x 16 = 8192 blocks
    dots_kernel<<<ga, 256, 0, stream>>>(x, Wtj, Gpart);

    out_kernel<<<NTOK / 16, 1024, 0, stream>>>(x, Gpart, bpre, bpost, bres,
                                               apre, apost, ares, out);
}